// Round 2
// baseline (256.656 us; speedup 1.0000x reference)
//
#include <hip/hip_runtime.h>

#define BB 32
#define TT 512
#define DD 768
#define NTHREADS 192            // = DD/4 float4 lanes per row
#define BLOCKS_PER_BATCH 64

// Native clang vector type — required by __builtin_nontemporal_store.
typedef float f4 __attribute__((ext_vector_type(4)));

// Output-row-balanced fused kernel (resubmit — round-1 bench was an infra
// failure, not a kernel verdict). Each block:
//  1. Redundantly computes its batch's reps = round(max(dur,0)) and the
//     512-wide inclusive scan in LDS (2 KB dur read is L2-hit, ~18 barriers
//     of trivial LDS work).
//  2. Owns a FIXED chunk of rpb = ceil(t_out/64) output rows. Writes are
//     perfectly balanced across blocks (the token-centric version wrote
//     0..192 KB per block, mean 96 KB — stragglers set completion time since
//     the whole grid is co-resident with no rebalancing).
//  3. Maps its first row to a source token via one binary search
//     (upper_bound over cum, broadcast LDS reads), then walks runs:
//     copy x[t] to rows [r, min(cum[t], rcopy)), prefetching the NEXT
//     source row one token ahead so its HBM latency hides under the current
//     run's non-temporal stores.
//  4. Rows >= total in its chunk get zeros (same ownership, no extra pass).
__global__ __launch_bounds__(NTHREADS) void lr_balanced_kernel(
    const float* __restrict__ x, const float* __restrict__ dur,
    float* __restrict__ out, int t_out, int rpb) {
    __shared__ int scum[TT];
    const int b = blockIdx.y;
    const int tid = threadIdx.x;

    const int r0 = blockIdx.x * rpb;
    const int r1 = (r0 + rpb < t_out) ? (r0 + rpb) : t_out;
    if (r0 >= r1) return;                 // uniform; before any barrier

    // reps into LDS
    for (int i = tid; i < TT; i += NTHREADS) {
        float d = fmaxf(dur[b * TT + i], 0.0f);
        scum[i] = (int)floorf(d + 0.5f);
    }
    __syncthreads();

    // Hillis-Steele inclusive scan over 512 elements with 192 threads.
    #pragma unroll
    for (int off = 1; off < TT; off <<= 1) {
        const int i0 = tid, i1 = tid + NTHREADS, i2 = tid + 2 * NTHREADS;
        int v0 = (i0 >= off) ? scum[i0 - off] : 0;
        int v1 = (i1 >= off) ? scum[i1 - off] : 0;
        int v2 = (i2 < TT && i2 >= off) ? scum[i2 - off] : 0;
        __syncthreads();
        scum[i0] += v0;
        scum[i1] += v1;
        if (i2 < TT) scum[i2] += v2;
        __syncthreads();
    }

    const int total = scum[TT - 1];
    const f4* xb = (const f4*)(x + (size_t)b * TT * DD);
    f4* ob = (f4*)(out + (size_t)b * (size_t)t_out * DD) + tid;

    const int rcopy = (r1 < total) ? r1 : total;
    int r = r0;

    if (r < rcopy) {
        // upper_bound(scum, r0): first t with cum[t] > r0 (== searchsorted
        // 'right'). r0 < total guarantees t < TT. Broadcast LDS reads.
        int lo = 0, hi = TT;
        while (lo < hi) {
            int mid = (lo + hi) >> 1;
            if (scum[mid] <= r) lo = mid + 1; else hi = mid;
        }
        int t = lo;

        f4 v = xb[(size_t)t * NTHREADS + tid];
        f4* op = ob + (size_t)r * NTHREADS;
        for (;;) {
            int stop = scum[t];
            if (stop >= rcopy) {          // last run in this chunk
                for (; r < rcopy; ++r, op += NTHREADS)
                    __builtin_nontemporal_store(v, op);
                break;
            }
            // find next token with reps > 0; stop < total so tn < TT
            int tn = t + 1;
            while (scum[tn] <= stop) ++tn;
            const f4 vn = xb[(size_t)tn * NTHREADS + tid];  // prefetch next row
            for (; r < stop; ++r, op += NTHREADS)
                __builtin_nontemporal_store(v, op);
            v = vn; t = tn;
        }
    }

    // zero tail inside this chunk: rows [max(r0,total), r1)
    const int z0 = (r0 > total) ? r0 : total;
    const f4 z = (f4)(0.0f);
    f4* opz = ob + (size_t)z0 * NTHREADS;
    for (int rz = z0; rz < r1; ++rz, opz += NTHREADS)
        __builtin_nontemporal_store(z, opz);
}

extern "C" void kernel_launch(void* const* d_in, const int* in_sizes, int n_in,
                              void* d_out, int out_size, void* d_ws, size_t ws_size,
                              hipStream_t stream) {
    const float* x   = (const float*)d_in[0];
    const float* dur = (const float*)d_in[1];
    float* out = (float*)d_out;
    (void)d_ws; (void)ws_size; (void)in_sizes; (void)n_in;

    const int t_out = out_size / (BB * DD);
    const int rpb = (t_out + BLOCKS_PER_BATCH - 1) / BLOCKS_PER_BATCH;

    dim3 grid(BLOCKS_PER_BATCH, BB);       // 64 x 32 blocks
    lr_balanced_kernel<<<grid, NTHREADS, 0, stream>>>(x, dur, out, t_out, rpb);
}